// Round 2
// baseline (569.651 us; speedup 1.0000x reference)
//
#include <hip/hip_runtime.h>
#include <hip/hip_bf16.h>
#include <math.h>

// Problem dims (fixed): T=512, B=256, I=128, H=256
#define TT 512
#define BB 256
#define II 128
#define HH 256

// ---------------------------------------------------------------------------
// Kernel 1: input projection  xi[m][n] = sum_k x[m][k]*Wi[n][k] + bh[n]
//   M = T*B = 131072, K = 128, N = 256. Written into d_out (later overwritten
//   in-place by the recurrence with h_t).
// ---------------------------------------------------------------------------
__global__ __launch_bounds__(256) void proj_kernel(
    const float* __restrict__ x, const float* __restrict__ Wi,
    const float* __restrict__ bh, float* __restrict__ out)
{
    __shared__ float xt[128][68];
    __shared__ float wt[128][64];

    const int tid = threadIdx.x;
    const int m0 = blockIdx.x * 64;
    const int j0 = blockIdx.y * 64;

    {
        const int r  = tid & 63;
        const int kc = tid >> 6;
        const float* xsrc = x  + (size_t)(m0 + r) * II + kc * 32;
        const float* wsrc = Wi + (size_t)(j0 + r) * II + kc * 32;
#pragma unroll
        for (int u = 0; u < 8; ++u) {
            float4 v = *(const float4*)(xsrc + u * 4);
            int k = kc * 32 + u * 4;
            xt[k + 0][r] = v.x; xt[k + 1][r] = v.y;
            xt[k + 2][r] = v.z; xt[k + 3][r] = v.w;
        }
#pragma unroll
        for (int u = 0; u < 8; ++u) {
            float4 v = *(const float4*)(wsrc + u * 4);
            int k = kc * 32 + u * 4;
            wt[k + 0][r] = v.x; wt[k + 1][r] = v.y;
            wt[k + 2][r] = v.z; wt[k + 3][r] = v.w;
        }
    }
    __syncthreads();

    const int ty = tid >> 4, tx = tid & 15;
    const int r0 = ty * 4, c0 = tx * 4;
    float acc[4][4] = {};
#pragma unroll 4
    for (int k = 0; k < 128; ++k) {
        float4 a = *(const float4*)&xt[k][r0];
        float4 b = *(const float4*)&wt[k][c0];
        float av[4] = {a.x, a.y, a.z, a.w};
        float bv[4] = {b.x, b.y, b.z, b.w};
#pragma unroll
        for (int i = 0; i < 4; ++i)
#pragma unroll
            for (int j = 0; j < 4; ++j)
                acc[i][j] += av[i] * bv[j];
    }

    float4 bias = *(const float4*)(bh + j0 + c0);
    float bvv[4] = {bias.x, bias.y, bias.z, bias.w};
#pragma unroll
    for (int i = 0; i < 4; ++i) {
        float4 o;
        o.x = acc[i][0] + bvv[0];
        o.y = acc[i][1] + bvv[1];
        o.z = acc[i][2] + bvv[2];
        o.w = acc[i][3] + bvv[3];
        *(float4*)(out + (size_t)(m0 + r0 + i) * HH + j0 + c0) = o;
    }
}

// ---------------------------------------------------------------------------
// tanh(x) = 1 - 2/(exp(2x)+1), via v_exp_f32 + v_rcp_f32.
// Saturates correctly at +/-1 for large |x|; abs error ~1e-6.
// ---------------------------------------------------------------------------
__device__ __forceinline__ float fast_tanh(float x) {
    float e = __expf(2.0f * x);
    return 1.0f - 2.0f * __builtin_amdgcn_rcpf(e + 1.0f);
}

// ---------------------------------------------------------------------------
// Kernel 2: recurrence. One block per batch row. 512 threads = 8 waves.
//   FMA phase: thread (lane, wave kq) owns 4 cols (lane*4..+4) x 32-k slice
//   (kq*32..+32); Wh fragment pinned in 128 VGPRs (asm keep-alive stops the
//   compiler from sinking the loads into the loop — round-1 showed VGPR=80,
//   i.e. Wh was being re-fetched every step).
//   Reduce phase: ALL 8 waves; wave q owns cols [32q,32q+32): 4 ds_read_b32
//   (2-way bank alias = free) + shfl_xor(32) + fast_tanh on lanes<32.
//   Global h-store deferred to the TOP of the next step so the
//   vmcnt(0)-before-barrier drain happens ~600cyc after issue (hidden).
// ---------------------------------------------------------------------------
__global__ __launch_bounds__(512, 2) void rec_kernel(
    const float* __restrict__ Wh, const float* __restrict__ h0,
    float* __restrict__ io)
{
    __shared__ float h[HH];
    __shared__ float part[8][HH];

    const int tid  = threadIdx.x;
    const int b    = blockIdx.x;
    const int lane = tid & 63;
    const int kq   = tid >> 6;     // wave id, 0..7
    const int jb   = lane * 4;     // FMA phase: first of 4 output columns
    const int kb   = kq * 32;      // FMA phase: k-slice base

    const int half = lane >> 5;              // reduce: partial-half 0/1
    const int col  = (kq << 5) + (lane & 31); // reduce: wave q owns 32 cols
    const bool lo  = (lane < 32);

    // persistent Wh fragment: 4 cols x 32 k = 32 float4 = 128 VGPRs
    float4 w[4][8];
#pragma unroll
    for (int c = 0; c < 4; ++c)
#pragma unroll
        for (int m = 0; m < 8; ++m)
            w[c][m] = *(const float4*)(Wh + (size_t)(jb + c) * HH + kb + m * 4);
    // pin in registers: uses now depend on asm outputs, so the loads cannot
    // be rematerialized inside the time loop.
#pragma unroll
    for (int c = 0; c < 4; ++c)
#pragma unroll
        for (int m = 0; m < 8; ++m)
            asm volatile("" : "+v"(w[c][m].x), "+v"(w[c][m].y),
                              "+v"(w[c][m].z), "+v"(w[c][m].w));

    if (tid < HH) h[tid] = h0[(size_t)b * HH + tid];
    __syncthreads();

    const size_t stride = (size_t)BB * HH;
    size_t ofs = (size_t)b * HH;
    float hn = 0.0f;

    for (int t = 0; t < TT; ++t) {
        // store h_{t-1} (issued early, drains under the FMA phase) and
        // prefetch xi_t (consumed in the reduce phase)
        float xr = 0.0f;
        if (lo) {
            if (t) io[ofs - stride + col] = hn;
            xr = io[ofs + col];
        }

        // broadcast-read current h k-slice (wave-uniform addresses)
        float4 hv[8];
#pragma unroll
        for (int m = 0; m < 8; ++m)
            hv[m] = *(const float4*)&h[kb + m * 4];

        float acc[4];
#pragma unroll
        for (int c = 0; c < 4; ++c) {
            float s = 0.f;
#pragma unroll
            for (int m = 0; m < 8; ++m) {
                s += w[c][m].x * hv[m].x;
                s += w[c][m].y * hv[m].y;
                s += w[c][m].z * hv[m].z;
                s += w[c][m].w * hv[m].w;
            }
            acc[c] = s;
        }
        *(float4*)&part[kq][jb] = make_float4(acc[0], acc[1], acc[2], acc[3]);
        __syncthreads();

        // distributed reduce: 4 partials per half, then cross-half shuffle
        const float* pp = &part[half * 4][col];
        float s = pp[0] + pp[HH] + pp[2 * HH] + pp[3 * HH];
        s += __shfl_xor(s, 32);
        if (lo) {
            hn = fast_tanh(xr + s);
            h[col] = hn;
        }
        __syncthreads();
        ofs += stride;
    }
    if (lo) io[ofs - stride + col] = hn;   // final h store
}

extern "C" void kernel_launch(void* const* d_in, const int* in_sizes, int n_in,
                              void* d_out, int out_size, void* d_ws, size_t ws_size,
                              hipStream_t stream) {
    const float* x  = (const float*)d_in[0];  // [T,B,I]
    const float* h0 = (const float*)d_in[1];  // [B,H]
    const float* Wi = (const float*)d_in[2];  // [H,I]
    const float* Wh = (const float*)d_in[3];  // [H,H]
    const float* bh = (const float*)d_in[4];  // [H]
    float* out = (float*)d_out;               // [T,B,H]

    dim3 pgrid(TT * BB / 64, HH / 64);
    proj_kernel<<<pgrid, 256, 0, stream>>>(x, Wi, bh, out);
    rec_kernel<<<BB, 512, 0, stream>>>(Wh, h0, out);
}

// Round 3
// 462.446 us; speedup vs baseline: 1.2318x; 1.2318x over previous
//
#include <hip/hip_runtime.h>
#include <hip/hip_bf16.h>
#include <math.h>

// Problem dims (fixed): T=512, B=256, I=128, H=256
#define TT 512
#define BB 256
#define II 128
#define HH 256

typedef float f4 __attribute__((ext_vector_type(4)));

// ---------------------------------------------------------------------------
// Kernel 1: input projection  xi[m][n] = sum_k x[m][k]*Wi[n][k] + bh[n]
//   M = T*B = 131072, K = 128, N = 256. Written into d_out (later overwritten
//   in-place by the recurrence with h_t).
// ---------------------------------------------------------------------------
__global__ __launch_bounds__(256) void proj_kernel(
    const float* __restrict__ x, const float* __restrict__ Wi,
    const float* __restrict__ bh, float* __restrict__ out)
{
    __shared__ float xt[128][68];
    __shared__ float wt[128][64];

    const int tid = threadIdx.x;
    const int m0 = blockIdx.x * 64;
    const int j0 = blockIdx.y * 64;

    {
        const int r  = tid & 63;
        const int kc = tid >> 6;
        const float* xsrc = x  + (size_t)(m0 + r) * II + kc * 32;
        const float* wsrc = Wi + (size_t)(j0 + r) * II + kc * 32;
#pragma unroll
        for (int u = 0; u < 8; ++u) {
            float4 v = *(const float4*)(xsrc + u * 4);
            int k = kc * 32 + u * 4;
            xt[k + 0][r] = v.x; xt[k + 1][r] = v.y;
            xt[k + 2][r] = v.z; xt[k + 3][r] = v.w;
        }
#pragma unroll
        for (int u = 0; u < 8; ++u) {
            float4 v = *(const float4*)(wsrc + u * 4);
            int k = kc * 32 + u * 4;
            wt[k + 0][r] = v.x; wt[k + 1][r] = v.y;
            wt[k + 2][r] = v.z; wt[k + 3][r] = v.w;
        }
    }
    __syncthreads();

    const int ty = tid >> 4, tx = tid & 15;
    const int r0 = ty * 4, c0 = tx * 4;
    float acc[4][4] = {};
#pragma unroll 4
    for (int k = 0; k < 128; ++k) {
        float4 a = *(const float4*)&xt[k][r0];
        float4 b = *(const float4*)&wt[k][c0];
        float av[4] = {a.x, a.y, a.z, a.w};
        float bv[4] = {b.x, b.y, b.z, b.w};
#pragma unroll
        for (int i = 0; i < 4; ++i)
#pragma unroll
            for (int j = 0; j < 4; ++j)
                acc[i][j] += av[i] * bv[j];
    }

    float4 bias = *(const float4*)(bh + j0 + c0);
    float bvv[4] = {bias.x, bias.y, bias.z, bias.w};
#pragma unroll
    for (int i = 0; i < 4; ++i) {
        float4 o;
        o.x = acc[i][0] + bvv[0];
        o.y = acc[i][1] + bvv[1];
        o.z = acc[i][2] + bvv[2];
        o.w = acc[i][3] + bvv[3];
        *(float4*)(out + (size_t)(m0 + r0 + i) * HH + j0 + c0) = o;
    }
}

// ---------------------------------------------------------------------------
// tanh(x) = 1 - 2/(exp(2x)+1). abs error ~1e-6, saturates correctly.
// ---------------------------------------------------------------------------
__device__ __forceinline__ float fast_tanh(float x) {
    float e = __expf(2.0f * x);
    return 1.0f - 2.0f * __builtin_amdgcn_rcpf(e + 1.0f);
}

// Opaque (un-rematerializable, un-sinkable) 16B global load.
// Round-1: compiler re-sank plain loads into the time loop (VGPR=80).
// Round-2: "+v" asm on float4 members broke SROA -> array in scratch
// (VGPR=84, 477us). This form produces clean SSA values from asm.
__device__ __forceinline__ f4 ld_f4_opaque(const float* p) {
    f4 r;
    asm volatile("global_load_dwordx4 %0, %1, off"
                 : "=v"(r) : "v"(p));
    return r;
}

// ---------------------------------------------------------------------------
// Kernel 2: recurrence. One block per batch row. 512 threads = 8 waves.
//   FMA phase: thread (lane, wave kq) owns 4 cols (lane*4..+4) x 32-k slice
//   (kq*32..+32); Wh fragment held in 128 VGPRs via opaque asm loads.
//   h k-slice reads are wave-uniform LDS addresses -> broadcast (free).
//   Reduce phase: wave q owns cols [32q,32q+32); 4 ds_read + shfl_xor(32)
//   + fast_tanh on lanes<32. Global h-store deferred to the next step's
//   FMA phase so the vmcnt-before-barrier drain is hidden.
// ---------------------------------------------------------------------------
__global__ __launch_bounds__(512, 2) void rec_kernel(
    const float* __restrict__ Wh, const float* __restrict__ h0,
    float* __restrict__ io)
{
    __shared__ float h[HH];
    __shared__ float part[8][HH];

    const int tid  = threadIdx.x;
    const int b    = blockIdx.x;
    const int lane = tid & 63;
    const int kq   = tid >> 6;     // wave id, 0..7
    const int jb   = lane * 4;     // FMA phase: first of 4 output columns
    const int kb   = kq * 32;      // FMA phase: k-slice base

    const int half = lane >> 5;               // reduce: partial-half 0/1
    const int col  = (kq << 5) + (lane & 31); // reduce: wave q owns 32 cols
    const bool lo  = (lane < 32);

    // persistent Wh fragment: 4 cols x 32 k = 32 float4 = 128 VGPRs,
    // loaded via opaque asm so they CANNOT be rematerialized in the loop.
    f4 w[4][8];
#pragma unroll
    for (int c = 0; c < 4; ++c)
#pragma unroll
        for (int m = 0; m < 8; ++m)
            w[c][m] = ld_f4_opaque(Wh + (size_t)(jb + c) * HH + kb + m * 4);
    asm volatile("s_waitcnt vmcnt(0)" ::: "memory");
    __builtin_amdgcn_sched_barrier(0);   // rule #18: keep uses after waitcnt

    if (tid < HH) h[tid] = h0[(size_t)b * HH + tid];
    __syncthreads();

    const size_t stride = (size_t)BB * HH;
    size_t ofs = (size_t)b * HH;
    float hn = 0.0f;

    for (int t = 0; t < TT; ++t) {
        // store h_{t-1} (drains under this step's FMA phase) and
        // prefetch xi_t (consumed in the reduce phase)
        float xr = 0.0f;
        if (lo) {
            if (t) io[ofs - stride + col] = hn;
            xr = io[ofs + col];
        }

        // wave-uniform broadcast read of current h k-slice
        f4 hv[8];
#pragma unroll
        for (int m = 0; m < 8; ++m)
            hv[m] = *(const f4*)&h[kb + m * 4];

        float acc[4];
#pragma unroll
        for (int c = 0; c < 4; ++c) {
            float s = 0.f;
#pragma unroll
            for (int m = 0; m < 8; ++m) {
                s += w[c][m].x * hv[m].x;
                s += w[c][m].y * hv[m].y;
                s += w[c][m].z * hv[m].z;
                s += w[c][m].w * hv[m].w;
            }
            acc[c] = s;
        }
        *(f4*)&part[kq][jb] = (f4){acc[0], acc[1], acc[2], acc[3]};
        __syncthreads();

        // distributed reduce: 4 partials per half, then cross-half shuffle
        const float* pp = &part[half * 4][col];
        float s = pp[0] + pp[HH] + pp[2 * HH] + pp[3 * HH];
        s += __shfl_xor(s, 32);
        if (lo) {
            hn = fast_tanh(xr + s);
            h[col] = hn;
        }
        __syncthreads();
        ofs += stride;
    }
    if (lo) io[ofs - stride + col] = hn;   // final h store
}

extern "C" void kernel_launch(void* const* d_in, const int* in_sizes, int n_in,
                              void* d_out, int out_size, void* d_ws, size_t ws_size,
                              hipStream_t stream) {
    const float* x  = (const float*)d_in[0];  // [T,B,I]
    const float* h0 = (const float*)d_in[1];  // [B,H]
    const float* Wi = (const float*)d_in[2];  // [H,I]
    const float* Wh = (const float*)d_in[3];  // [H,H]
    const float* bh = (const float*)d_in[4];  // [H]
    float* out = (float*)d_out;               // [T,B,H]

    dim3 pgrid(TT * BB / 64, HH / 64);
    proj_kernel<<<pgrid, 256, 0, stream>>>(x, Wi, bh, out);
    rec_kernel<<<BB, 512, 0, stream>>>(Wh, h0, out);
}